// Round 1
// baseline (308.840 us; speedup 1.0000x reference)
//
#include <hip/hip_runtime.h>
#include <hip/hip_bf16.h>

#define Bn 16
#define Cn 64
#define Nn 4096

typedef __attribute__((ext_vector_type(8))) short bf16x8;
typedef __attribute__((ext_vector_type(4))) float f32x4;

__device__ __forceinline__ unsigned short f2bf(float f) {
    union { float f; unsigned int u; } v; v.f = f;
    unsigned int r = (v.u + 0x7fffu + ((v.u >> 16) & 1u)) >> 16;
    return (unsigned short)r;
}

// ---------------- Stage 1: 1x1 convs -> Q [B][N][32], K [B][N][32] (bf16 row-major),
// V [B][64][N] (bf16, c-major == c3 natural layout) ----------------
__global__ __launch_bounds__(256) void qkv_kernel(
    const float* __restrict__ x,
    const float* __restrict__ w1,   // -> c1 -> K
    const float* __restrict__ w2,   // -> c2 -> Q
    const float* __restrict__ w3,   // -> c3 -> V
    unsigned short* __restrict__ Qw,
    unsigned short* __restrict__ Kw,
    unsigned short* __restrict__ Vw)
{
    const int t = blockIdx.x * 256 + threadIdx.x;   // global position index over B*N
    const int b = t >> 12;
    const int n = t & (Nn - 1);
    const float* xb = x + (size_t)b * Cn * Nn + n;
    float xr[Cn];
    #pragma unroll
    for (int c = 0; c < Cn; ++c) xr[c] = xb[(size_t)c * Nn];

    // K rows from w1
    unsigned short* krow = Kw + ((size_t)b * Nn + n) * 32;
    #pragma unroll 1
    for (int d8 = 0; d8 < 32; d8 += 8) {
        unsigned int u[4];
        #pragma unroll
        for (int i = 0; i < 4; ++i) {
            float a0 = 0.f, a1 = 0.f;
            const float* wr0 = w1 + (d8 + 2 * i) * 64;
            const float* wr1 = w1 + (d8 + 2 * i + 1) * 64;
            #pragma unroll
            for (int c = 0; c < 64; ++c) {
                a0 = fmaf(wr0[c], xr[c], a0);
                a1 = fmaf(wr1[c], xr[c], a1);
            }
            u[i] = (unsigned int)f2bf(a0) | ((unsigned int)f2bf(a1) << 16);
        }
        *(uint4*)(krow + d8) = make_uint4(u[0], u[1], u[2], u[3]);
    }
    // Q rows from w2
    unsigned short* qrow = Qw + ((size_t)b * Nn + n) * 32;
    #pragma unroll 1
    for (int d8 = 0; d8 < 32; d8 += 8) {
        unsigned int u[4];
        #pragma unroll
        for (int i = 0; i < 4; ++i) {
            float a0 = 0.f, a1 = 0.f;
            const float* wr0 = w2 + (d8 + 2 * i) * 64;
            const float* wr1 = w2 + (d8 + 2 * i + 1) * 64;
            #pragma unroll
            for (int c = 0; c < 64; ++c) {
                a0 = fmaf(wr0[c], xr[c], a0);
                a1 = fmaf(wr1[c], xr[c], a1);
            }
            u[i] = (unsigned int)f2bf(a0) | ((unsigned int)f2bf(a1) << 16);
        }
        *(uint4*)(qrow + d8) = make_uint4(u[0], u[1], u[2], u[3]);
    }
    // V from w3, stored c-major: Vw[b][d][n]
    #pragma unroll 1
    for (int d = 0; d < 64; ++d) {
        float a = 0.f;
        const float* wr = w3 + d * 64;
        #pragma unroll
        for (int c = 0; c < 64; ++c) a = fmaf(wr[c], xr[c], a);
        Vw[((size_t)b * 64 + d) * Nn + n] = f2bf(a);
    }
}

// ---------------- Stage 2: flash attention + epilogue ----------------
// grid (N/64, B), block 256 (4 waves, 16 q-rows each). KVBLK=64.
#define KPAD 40   // K lds row stride in shorts (80 B)  -> 2-way banks on b128 reads
#define VPAD 72   // VT lds row stride in shorts (144 B) -> 2-way banks
#define PPAD 72

__global__ __launch_bounds__(256) void attn_kernel(
    const unsigned short* __restrict__ Q,
    const unsigned short* __restrict__ K,
    const unsigned short* __restrict__ V,    // [B][64][N] (c-major == V^T rows)
    const float* __restrict__ x,
    const float* __restrict__ gamma,
    float* __restrict__ out)
{
    __shared__ unsigned short Klds[64 * KPAD];
    __shared__ unsigned short Vlds[64 * VPAD];
    __shared__ unsigned short Plds[4][16 * PPAD];

    const int tid  = threadIdx.x;
    const int wave = tid >> 6;
    const int lane = tid & 63;
    const int lo = lane & 15;
    const int hi = lane >> 4;

    const int b = blockIdx.y;
    const int qbase = blockIdx.x * 64 + wave * 16;

    // Q fragment: A-layout, lane holds Q[qbase+lo][hi*8 .. hi*8+7]
    const bf16x8 qf = *(const bf16x8*)(Q + ((size_t)b * Nn + qbase + lo) * 32 + hi * 8);

    const unsigned short* Kb = K + (size_t)b * Nn * 32;
    const unsigned short* Vb = V + (size_t)b * 64 * Nn;

    float m[4], l[4];
    f32x4 o[4] = {};
    #pragma unroll
    for (int r = 0; r < 4; ++r) { m[r] = -1e30f; l[r] = 0.f; }
    const f32x4 zero4 = {0.f, 0.f, 0.f, 0.f};

    for (int kv = 0; kv < Nn; kv += 64) {
        __syncthreads();   // previous tile fully consumed
        {   // stage K tile: rows [kv..kv+63] x 32
            int r = tid >> 2, s = tid & 3;
            uint4 kd = *(const uint4*)(Kb + (size_t)(kv + r) * 32 + s * 8);
            *(uint4*)(&Klds[r * KPAD + s * 8]) = kd;
        }
        {   // stage V^T tile: Vlds[c][j] = V[b][c][kv+j]
            int c = tid >> 2, s = tid & 3;
            const unsigned short* src = Vb + (size_t)c * Nn + kv + s * 16;
            uint4 v0 = *(const uint4*)(src);
            uint4 v1 = *(const uint4*)(src + 8);
            *(uint4*)(&Vlds[c * VPAD + s * 16])     = v0;
            *(uint4*)(&Vlds[c * VPAD + s * 16 + 8]) = v1;
        }
        __syncthreads();

        // S = Q K^T  (16 rows x 64 cols per wave, 4 col-tiles)
        f32x4 s4[4];
        #pragma unroll
        for (int kt = 0; kt < 4; ++kt) {
            bf16x8 kf = *(const bf16x8*)(&Klds[(kt * 16 + lo) * KPAD + hi * 8]);
            s4[kt] = __builtin_amdgcn_mfma_f32_16x16x32_bf16(qf, kf, zero4, 0, 0, 0);
        }

        // online softmax (rows live on reg r, spread over 16 lanes)
        float mnew[4], scale[4];
        #pragma unroll
        for (int r = 0; r < 4; ++r) {
            float mx = fmaxf(fmaxf(s4[0][r], s4[1][r]), fmaxf(s4[2][r], s4[3][r]));
            #pragma unroll
            for (int sh = 1; sh <= 8; sh <<= 1)
                mx = fmaxf(mx, __shfl_xor(mx, sh, 64));
            mnew[r] = fmaxf(m[r], mx);
            scale[r] = __expf(m[r] - mnew[r]);
        }
        #pragma unroll
        for (int ct = 0; ct < 4; ++ct) {
            #pragma unroll
            for (int r = 0; r < 4; ++r)
                s4[ct][r] = __expf(s4[ct][r] - mnew[r]);
        }
        #pragma unroll
        for (int r = 0; r < 4; ++r) {
            float sm = (s4[0][r] + s4[1][r]) + (s4[2][r] + s4[3][r]);
            #pragma unroll
            for (int sh = 1; sh <= 8; sh <<= 1)
                sm += __shfl_xor(sm, sh, 64);
            l[r] = l[r] * scale[r] + sm;
            m[r] = mnew[r];
        }
        #pragma unroll
        for (int ct = 0; ct < 4; ++ct)
            #pragma unroll
            for (int r = 0; r < 4; ++r) o[ct][r] *= scale[r];

        // P -> LDS (wave-private), re-layout C-frag -> A-frag
        unsigned short* P = Plds[wave];
        #pragma unroll
        for (int ct = 0; ct < 4; ++ct)
            #pragma unroll
            for (int r = 0; r < 4; ++r)
                P[(hi * 4 + r) * PPAD + ct * 16 + lo] = f2bf(s4[ct][r]);

        // O += P V   (K-dim 64 = 2 chunks)
        bf16x8 pa0 = *(const bf16x8*)(&P[lo * PPAD + hi * 8]);
        bf16x8 pa1 = *(const bf16x8*)(&P[lo * PPAD + 32 + hi * 8]);
        #pragma unroll
        for (int ct = 0; ct < 4; ++ct) {
            bf16x8 vb0 = *(const bf16x8*)(&Vlds[(ct * 16 + lo) * VPAD + hi * 8]);
            bf16x8 vb1 = *(const bf16x8*)(&Vlds[(ct * 16 + lo) * VPAD + 32 + hi * 8]);
            o[ct] = __builtin_amdgcn_mfma_f32_16x16x32_bf16(pa0, vb0, o[ct], 0, 0, 0);
            o[ct] = __builtin_amdgcn_mfma_f32_16x16x32_bf16(pa1, vb1, o[ct], 0, 0, 0);
        }
    }

    // epilogue: out[b][c][n] = gamma * O[n][c] / l[n] + x[b][c][n]
    const float g = gamma[0];
    float rl[4];
    #pragma unroll
    for (int r = 0; r < 4; ++r) rl[r] = 1.0f / l[r];
    #pragma unroll
    for (int ct = 0; ct < 4; ++ct) {
        int c = ct * 16 + lo;
        size_t idx = ((size_t)b * 64 + c) * Nn + qbase + hi * 4;  // 4 consecutive n in regs r
        float4 xv = *(const float4*)(x + idx);
        float4 ov;
        ov.x = g * (o[ct][0] * rl[0]) + xv.x;
        ov.y = g * (o[ct][1] * rl[1]) + xv.y;
        ov.z = g * (o[ct][2] * rl[2]) + xv.z;
        ov.w = g * (o[ct][3] * rl[3]) + xv.w;
        *(float4*)(out + idx) = ov;
    }
}

extern "C" void kernel_launch(void* const* d_in, const int* in_sizes, int n_in,
                              void* d_out, int out_size, void* d_ws, size_t ws_size,
                              hipStream_t stream) {
    const float* x     = (const float*)d_in[0];
    const float* w1    = (const float*)d_in[1];
    const float* w2    = (const float*)d_in[2];
    const float* w3    = (const float*)d_in[3];
    const float* gamma = (const float*)d_in[4];
    float* out = (float*)d_out;

    unsigned short* Qw = (unsigned short*)d_ws;                 // 4 MB
    unsigned short* Kw = Qw + (size_t)Bn * Nn * 32;             // 4 MB
    unsigned short* Vw = Kw + (size_t)Bn * Nn * 32;             // 8 MB

    qkv_kernel<<<dim3(Bn * Nn / 256), 256, 0, stream>>>(x, w1, w2, w3, Qw, Kw, Vw);
    attn_kernel<<<dim3(Nn / 64, Bn), 256, 0, stream>>>(Qw, Kw, Vw, x, gamma, out);
}

// Round 4
// 241.612 us; speedup vs baseline: 1.2782x; 1.2782x over previous
//
#include <hip/hip_runtime.h>
#include <hip/hip_bf16.h>

#define Bn 16
#define Nn 4096
#define LOG2E 1.44269504088896f

typedef __attribute__((ext_vector_type(8))) short bf16x8;
typedef __attribute__((ext_vector_type(16))) float f32x16;

static __device__ __forceinline__ unsigned short f2bf(float f) {
    union { float f; unsigned int u; } v; v.f = f;
    return (unsigned short)((v.u + 0x7fffu + ((v.u >> 16) & 1u)) >> 16);
}
static __device__ __forceinline__ int cvtpk(float lo, float hi) {
    int d; asm("v_cvt_pk_bf16_f32 %0, %1, %2" : "=v"(d) : "v"(lo), "v"(hi)); return d;
}
static __device__ __forceinline__ bf16x8 mkfrag(int a, int b, int c, int d) {
    union { int i[4]; bf16x8 v; } u; u.i[0]=a; u.i[1]=b; u.i[2]=c; u.i[3]=d; return u.v;
}

// ---------------- Stage 1: 1x1 convs -> fragment-packed Qf/Kf/Vf (bf16) -------------
// Qf/Kf: [b][ntile(128)][dt(2)][lane(64)] uint4 : lane holds M[ntile*32+(lane&31)][dt*16+(lane>>5)*8 ..+7]
// Vf:    [b][kvtile(128)][ct(2)][jt(2)][lane(64)] uint4 :
//        lane holds V[ct*32+(lane&31)][kvtile*32 + jt*16 + (lane>>5)*8 ..+7]   (V = c3, c-major)
__global__ __launch_bounds__(256) void qkv_kernel(
    const float* __restrict__ x,
    const float* __restrict__ w1,
    const float* __restrict__ w2,
    const float* __restrict__ w3,
    uint4* __restrict__ Qf,
    uint4* __restrict__ Kf,
    uint4* __restrict__ Vf)
{
    __shared__ __align__(16) unsigned short vtile[64][136];  // 64 c x 128 n (+8 pad)

    const int t = threadIdx.x;
    const int half = t >> 7;
    const int nl = t & 127;
    const int b = blockIdx.x >> 5;                // 32 blocks per batch
    const int n = ((blockIdx.x & 31) << 7) + nl;  // position within batch
    const float* xb = x + ((size_t)b << 18) + n;

    float xr[64];
    #pragma unroll
    for (int c = 0; c < 64; ++c) xr[c] = xb[(size_t)c << 12];

    if (half == 0) {
        const int ntile = ((blockIdx.x & 31) << 2) + (nl >> 5);
        uint4* kdst = Kf + (((size_t)b * 128 + ntile) * 2) * 64;
        uint4* qdst = Qf + (((size_t)b * 128 + ntile) * 2) * 64;
        #define CONV32_STORE(WPTR, DST) do {                                          \
            _Pragma("unroll")                                                         \
            for (int dt = 0; dt < 2; ++dt) {                                          \
                float acc[16];                                                        \
                _Pragma("unroll") for (int i = 0; i < 16; ++i) acc[i] = 0.f;          \
                _Pragma("unroll")                                                     \
                for (int c = 0; c < 64; ++c) {                                        \
                    const float xv = xr[c];                                           \
                    _Pragma("unroll")                                                 \
                    for (int i = 0; i < 16; ++i)                                      \
                        acc[i] = fmaf((WPTR)[(dt*16 + i)*64 + c], xv, acc[i]);        \
                }                                                                     \
                uint4 u0, u1;                                                         \
                u0.x = (unsigned)f2bf(acc[0])  | ((unsigned)f2bf(acc[1])  << 16);     \
                u0.y = (unsigned)f2bf(acc[2])  | ((unsigned)f2bf(acc[3])  << 16);     \
                u0.z = (unsigned)f2bf(acc[4])  | ((unsigned)f2bf(acc[5])  << 16);     \
                u0.w = (unsigned)f2bf(acc[6])  | ((unsigned)f2bf(acc[7])  << 16);     \
                u1.x = (unsigned)f2bf(acc[8])  | ((unsigned)f2bf(acc[9])  << 16);     \
                u1.y = (unsigned)f2bf(acc[10]) | ((unsigned)f2bf(acc[11]) << 16);     \
                u1.z = (unsigned)f2bf(acc[12]) | ((unsigned)f2bf(acc[13]) << 16);     \
                u1.w = (unsigned)f2bf(acc[14]) | ((unsigned)f2bf(acc[15]) << 16);     \
                (DST)[(size_t)dt*64 + (nl & 31)]      = u0;                           \
                (DST)[(size_t)dt*64 + 32 + (nl & 31)] = u1;                           \
            }                                                                         \
        } while (0)
        CONV32_STORE(w1, kdst);
        CONV32_STORE(w2, qdst);
        #undef CONV32_STORE
    } else {
        #pragma unroll
        for (int dg = 0; dg < 8; ++dg) {
            float acc[8];
            #pragma unroll
            for (int i = 0; i < 8; ++i) acc[i] = 0.f;
            #pragma unroll
            for (int c = 0; c < 64; ++c) {
                const float xv = xr[c];
                #pragma unroll
                for (int i = 0; i < 8; ++i)
                    acc[i] = fmaf(w3[(dg*8 + i)*64 + c], xv, acc[i]);
            }
            #pragma unroll
            for (int i = 0; i < 8; ++i) vtile[dg*8 + i][nl] = f2bf(acc[i]);
        }
    }
    __syncthreads();

    #pragma unroll
    for (int i = 0; i < 4; ++i) {
        const int slot = t * 4 + i;          // [kvt:2][ct:1][jt:1][l:6]
        const int l   = slot & 63;
        const int jt  = (slot >> 6) & 1;
        const int ct  = (slot >> 7) & 1;
        const int kvt = slot >> 8;           // 0..3 local kv tile
        const uint4 v = *(const uint4*)&vtile[ct*32 + (l & 31)]
                                            [kvt*32 + jt*16 + ((l >> 5) << 3)];
        const int kvtg = ((blockIdx.x & 31) << 2) + kvt;
        Vf[((((size_t)b * 128 + kvtg) * 2 + ct) * 2 + jt) * 64 + l] = v;
    }
}

// ---------------- Stage 2: flash attention, no LDS, no barriers -------------------
// Swapped QK^T: S^T = mfma(K,Q) -> lane owns one q-row (col = lane&31); partner = lane^32.
__global__ __launch_bounds__(256) void attn_kernel(
    const bf16x8* __restrict__ Qf,
    const bf16x8* __restrict__ Kf,
    const bf16x8* __restrict__ Vf,
    const float* __restrict__ x,
    const float* __restrict__ gamma,
    float* __restrict__ out)
{
    const int lane = threadIdx.x & 63;
    const int wv   = threadIdx.x >> 6;
    const int id   = blockIdx.x;
    const int b    = 2 * (id & 7) + ((id >> 3) >> 5);
    const int qblk = (id >> 3) & 31;
    const int qt   = qblk * 4 + wv;          // 0..127
    const bool hib = (lane >> 5) != 0;

    const bf16x8* Qp = Qf + ((size_t)(b * 128 + qt) * 2) * 64;
    const bf16x8  qf0 = Qp[lane];
    const bf16x8  qf1 = Qp[64 + lane];
    const bf16x8* Kp = Kf + (size_t)b * 128 * 2 * 64;
    const bf16x8* Vp = Vf + (size_t)b * 128 * 4 * 64;

    f32x16 o0 = {}, o1 = {};
    float m2 = -1e30f, l = 0.f;

    bf16x8 kf0 = Kp[lane],        kf1 = Kp[64 + lane];
    bf16x8 v00 = Vp[lane],        v01 = Vp[64 + lane];
    bf16x8 v10 = Vp[128 + lane],  v11 = Vp[192 + lane];

    for (int kvt = 0; kvt < 128; ++kvt) {
        const int nx = kvt + (kvt < 127);
        const bf16x8 nk0 = Kp[(size_t)(nx*2)*64 + lane];
        const bf16x8 nk1 = Kp[(size_t)(nx*2+1)*64 + lane];
        const bf16x8 nv00 = Vp[(size_t)(nx*4)*64 + lane];
        const bf16x8 nv01 = Vp[(size_t)(nx*4+1)*64 + lane];
        const bf16x8 nv10 = Vp[(size_t)(nx*4+2)*64 + lane];
        const bf16x8 nv11 = Vp[(size_t)(nx*4+3)*64 + lane];

        // S^T tile: rows = kpos (32), cols = q; D=32 -> 2 chained MFMAs
        f32x16 s;
        {
            f32x16 z = {};
            s = __builtin_amdgcn_mfma_f32_32x32x16_bf16(kf0, qf0, z, 0, 0, 0);
            s = __builtin_amdgcn_mfma_f32_32x32x16_bf16(kf1, qf1, s, 0, 0, 0);
        }

        // ---- in-register online softmax; pair-reduce via __shfl_xor(.,32) ----
        float mx = s[0];
        #pragma unroll
        for (int i = 1; i < 16; ++i) mx = fmaxf(mx, s[i]);
        mx = fmaxf(mx, __shfl_xor(mx, 32, 64));
        const float pm = mx * LOG2E;
        if (__any(pm > m2 + 8.0f)) {          // defer-max
            const float m2n = fmaxf(m2, pm);
            const float sc = exp2f(m2 - m2n);
            l *= sc;
            #pragma unroll
            for (int i = 0; i < 16; ++i) { o0[i] *= sc; o1[i] *= sc; }
            m2 = m2n;
        }
        float p[16];
        #pragma unroll
        for (int i = 0; i < 16; ++i) p[i] = exp2f(fmaf(s[i], LOG2E, -m2));
        float sm = 0.f;
        #pragma unroll
        for (int i = 0; i < 16; ++i) sm += p[i];
        l += sm + __shfl_xor(sm, 32, 64);

        // ---- P (C-frag) -> B-frag: lane<->lane^32 word exchange via shfl_xor ----
        // Lane (hi=0) owns kpos {0-3,8-11,16-19,24-27}; partner (hi=1) owns +4.
        // B-frag claim (consistent with V packing): lane holds kpos 8*hi + j (pf0),
        // 16 + 8*hi + j (pf1), j = 0..7.
        const int A0 = cvtpk(p[0],  p[1]),  A1 = cvtpk(p[2],  p[3]);
        const int B0 = cvtpk(p[4],  p[5]),  B1 = cvtpk(p[6],  p[7]);
        const int C0 = cvtpk(p[8],  p[9]),  C1 = cvtpk(p[10], p[11]);
        const int D0 = cvtpk(p[12], p[13]), D1 = cvtpk(p[14], p[15]);
        int w0, w1, w2, w3;
        {   int e0 = __shfl_xor(hib ? A0 : B0, 32, 64);
            int e1 = __shfl_xor(hib ? A1 : B1, 32, 64);
            w0 = hib ? e0 : A0;  w2 = hib ? B0 : e0;
            w1 = hib ? e1 : A1;  w3 = hib ? B1 : e1; }
        const bf16x8 pf0 = mkfrag(w0, w1, w2, w3);   // kpos 0..15 of tile
        {   int e0 = __shfl_xor(hib ? C0 : D0, 32, 64);
            int e1 = __shfl_xor(hib ? C1 : D1, 32, 64);
            w0 = hib ? e0 : C0;  w2 = hib ? D0 : e0;
            w1 = hib ? e1 : C1;  w3 = hib ? D1 : e1; }
        const bf16x8 pf1 = mkfrag(w0, w1, w2, w3);   // kpos 16..31

        // ---- O^T += V^T x P^T ----
        o0 = __builtin_amdgcn_mfma_f32_32x32x16_bf16(v00, pf0, o0, 0, 0, 0);
        o0 = __builtin_amdgcn_mfma_f32_32x32x16_bf16(v01, pf1, o0, 0, 0, 0);
        o1 = __builtin_amdgcn_mfma_f32_32x32x16_bf16(v10, pf0, o1, 0, 0, 0);
        o1 = __builtin_amdgcn_mfma_f32_32x32x16_bf16(v11, pf1, o1, 0, 0, 0);

        kf0 = nk0; kf1 = nk1;
        v00 = nv00; v01 = nv01; v10 = nv10; v11 = nv11;
    }

    // ---- epilogue: out[b][c][n] = g * O^T[c][q]/l + x[b][c][n], n = q ----
    const float g = gamma[0];
    const float rl = 1.0f / l;
    const int n = qt * 32 + (lane & 31);
    const int hi1 = lane >> 5;
    #pragma unroll
    for (int r = 0; r < 16; ++r) {
        const int c0r = (r & 3) + 8 * (r >> 2) + 4 * hi1;
        {
            const size_t idx = (((size_t)b * 64 + c0r) << 12) + n;
            out[idx] = g * o0[r] * rl + x[idx];
        }
        {
            const size_t idx = (((size_t)b * 64 + 32 + c0r) << 12) + n;
            out[idx] = g * o1[r] * rl + x[idx];
        }
    }
}

extern "C" void kernel_launch(void* const* d_in, const int* in_sizes, int n_in,
                              void* d_out, int out_size, void* d_ws, size_t ws_size,
                              hipStream_t stream) {
    const float* x     = (const float*)d_in[0];
    const float* w1    = (const float*)d_in[1];
    const float* w2    = (const float*)d_in[2];
    const float* w3    = (const float*)d_in[3];
    const float* gamma = (const float*)d_in[4];
    float* out = (float*)d_out;

    uint4* Qf = (uint4*)d_ws;                        // 4 MB
    uint4* Kf = Qf + (size_t)Bn * 128 * 2 * 64;      // 4 MB
    uint4* Vf = Kf + (size_t)Bn * 128 * 2 * 64;      // 8 MB

    qkv_kernel<<<512, 256, 0, stream>>>(x, w1, w2, w3, Qf, Kf, Vf);
    attn_kernel<<<512, 256, 0, stream>>>((const bf16x8*)Qf, (const bf16x8*)Kf,
                                         (const bf16x8*)Vf, x, gamma, out);
}

// Round 6
// 173.783 us; speedup vs baseline: 1.7772x; 1.3903x over previous
//
#include <hip/hip_runtime.h>
#include <hip/hip_bf16.h>

#define Bn 16
#define Nn 4096
#define LOG2E 1.44269504088896f

typedef __attribute__((ext_vector_type(8))) short bf16x8;
typedef __attribute__((ext_vector_type(16))) float f32x16;

static __device__ __forceinline__ unsigned short f2bf(float f) {
    union { float f; unsigned int u; } v; v.f = f;
    return (unsigned short)((v.u + 0x7fffu + ((v.u >> 16) & 1u)) >> 16);
}
static __device__ __forceinline__ int cvtpk(float lo, float hi) {
    int d; asm("v_cvt_pk_bf16_f32 %0, %1, %2" : "=v"(d) : "v"(lo), "v"(hi)); return d;
}
static __device__ __forceinline__ bf16x8 mkfrag(int a, int b, int c, int d) {
    union { int i[4]; bf16x8 v; } u; u.i[0]=a; u.i[1]=b; u.i[2]=c; u.i[3]=d; return u.v;
}

// ---------------- Stage 1: 1x1 convs -> fragment-packed Qf/Kf/Vf (bf16) -------------
// Qf/Kf: [b][ntile(128)][dt(2)][lane(64)] uint4 : lane holds M[ntile*32+(lane&31)][dt*16+(lane>>5)*8 ..+7]
// Vf: [b][kvtile(128)][ct(2)][jt(2)][lane(64)] uint4, k-order permuted to match the
//     QK^T C-frag order: slot j of lane = V[ct*32+(lane&31)]
//     [kvtile*32 + jt*16 + 4*(lane>>5) + (j&3) + 8*(j>>2)]
__global__ __launch_bounds__(256) void qkv_kernel(
    const float* __restrict__ x,
    const float* __restrict__ w1,
    const float* __restrict__ w2,
    const float* __restrict__ w3,
    uint4* __restrict__ Qf,
    uint4* __restrict__ Kf,
    uint4* __restrict__ Vf)
{
    __shared__ float wlds[128 * 64];                        // w1|w2|w3, 32 KB
    __shared__ __align__(16) unsigned short vtile[64][136]; // 64 c x 128 n (+8 pad)

    const int t = threadIdx.x;
    {   // stage weights to LDS (8 float4 per thread)
        float4* wd = (float4*)wlds;
        const float4* s1 = (const float4*)w1;
        const float4* s2 = (const float4*)w2;
        const float4* s3 = (const float4*)w3;
        wd[t]       = s1[t];
        wd[256 + t] = s1[256 + t];
        wd[512 + t] = s2[t];
        wd[768 + t] = s2[256 + t];
        #pragma unroll
        for (int k = 0; k < 4; ++k) wd[1024 + k * 256 + t] = s3[k * 256 + t];
    }

    const int half = t >> 7;
    const int nl = t & 127;
    const int b = blockIdx.x >> 5;
    const int n = ((blockIdx.x & 31) << 7) + nl;
    const float* xb = x + ((size_t)b << 18) + n;
    float xr[64];
    #pragma unroll
    for (int c = 0; c < 64; ++c) xr[c] = xb[(size_t)c << 12];

    __syncthreads();

    if (half == 0) {
        const int ntile = ((blockIdx.x & 31) << 2) + (nl >> 5);
        #pragma unroll
        for (int sel = 0; sel < 2; ++sel) {   // 0: K (w1), 1: Q (w2)
            const float* wbase = wlds + sel * 2048;
            uint4* dst = (sel ? Qf : Kf) + (((size_t)b * 128 + ntile) * 2) * 64;
            #pragma unroll
            for (int dt = 0; dt < 2; ++dt) {
                float acc[16];
                #pragma unroll
                for (int i = 0; i < 16; ++i) {
                    const float* wr = wbase + (dt * 16 + i) * 64;
                    float a = 0.f;
                    #pragma unroll
                    for (int c4 = 0; c4 < 16; ++c4) {
                        const float4 wv = *(const float4*)(wr + c4 * 4);
                        a = fmaf(wv.x, xr[c4 * 4 + 0], a);
                        a = fmaf(wv.y, xr[c4 * 4 + 1], a);
                        a = fmaf(wv.z, xr[c4 * 4 + 2], a);
                        a = fmaf(wv.w, xr[c4 * 4 + 3], a);
                    }
                    acc[i] = a;
                }
                uint4 u0, u1;
                u0.x = (unsigned)f2bf(acc[0])  | ((unsigned)f2bf(acc[1])  << 16);
                u0.y = (unsigned)f2bf(acc[2])  | ((unsigned)f2bf(acc[3])  << 16);
                u0.z = (unsigned)f2bf(acc[4])  | ((unsigned)f2bf(acc[5])  << 16);
                u0.w = (unsigned)f2bf(acc[6])  | ((unsigned)f2bf(acc[7])  << 16);
                u1.x = (unsigned)f2bf(acc[8])  | ((unsigned)f2bf(acc[9])  << 16);
                u1.y = (unsigned)f2bf(acc[10]) | ((unsigned)f2bf(acc[11]) << 16);
                u1.z = (unsigned)f2bf(acc[12]) | ((unsigned)f2bf(acc[13]) << 16);
                u1.w = (unsigned)f2bf(acc[14]) | ((unsigned)f2bf(acc[15]) << 16);
                dst[(size_t)dt * 64 + (nl & 31)]      = u0;
                dst[(size_t)dt * 64 + 32 + (nl & 31)] = u1;
            }
        }
    } else {
        #pragma unroll
        for (int dg = 0; dg < 8; ++dg) {
            #pragma unroll
            for (int i = 0; i < 8; ++i) {
                const float* wr = wlds + (64 + dg * 8 + i) * 64;
                float a = 0.f;
                #pragma unroll
                for (int c4 = 0; c4 < 16; ++c4) {
                    const float4 wv = *(const float4*)(wr + c4 * 4);
                    a = fmaf(wv.x, xr[c4 * 4 + 0], a);
                    a = fmaf(wv.y, xr[c4 * 4 + 1], a);
                    a = fmaf(wv.z, xr[c4 * 4 + 2], a);
                    a = fmaf(wv.w, xr[c4 * 4 + 3], a);
                }
                vtile[dg * 8 + i][nl] = f2bf(a);
            }
        }
    }
    __syncthreads();

    // Vf scatter with permuted k-order gather
    #pragma unroll
    for (int i = 0; i < 4; ++i) {
        const int slot = t * 4 + i;          // [kvt:2][ct:1][jt:1][l:6]
        const int l   = slot & 63;
        const int jt  = (slot >> 6) & 1;
        const int ct  = (slot >> 7) & 1;
        const int kvt = slot >> 8;
        const int row  = ct * 32 + (l & 31);
        const int base = kvt * 32 + jt * 16 + ((l >> 5) << 2);
        const uint2 lo = *(const uint2*)&vtile[row][base];      // k = 4h + 0..3
        const uint2 hi = *(const uint2*)&vtile[row][base + 8];  // k = 4h + 8..11
        const int kvtg = ((blockIdx.x & 31) << 2) + kvt;
        Vf[((((size_t)b * 128 + kvtg) * 2 + ct) * 2 + jt) * 64 + l] =
            make_uint4(lo.x, lo.y, hi.x, hi.y);
    }
}

// ---------------- Stage 2: flash attention, reg->LDS staged K/V, double-buffered ----
// grid 512 x 256 thr (4 waves); wave wv owns q-tile qt; tiles shared via LDS.
__global__ __launch_bounds__(256) void attn_kernel(
    const bf16x8* __restrict__ Qf,
    const bf16x8* __restrict__ Kf,
    const bf16x8* __restrict__ Vf,
    const float* __restrict__ x,
    const float* __restrict__ gamma,
    float* __restrict__ out)
{
    __shared__ __align__(16) unsigned char kvbuf[2 * 6144];  // 6 slots x 1 KB, x2 buffers

    const int t    = threadIdx.x;
    const int lane = t & 63;
    const int wv   = t >> 6;
    const int id   = blockIdx.x;
    const int b    = 2 * (id & 7) + ((id >> 3) >> 5);   // XCD-chunked batch map
    const int qblk = (id >> 3) & 31;
    const int qt   = qblk * 4 + wv;

    const bf16x8* Qp = Qf + ((size_t)(b * 128 + qt) * 2) * 64;
    const bf16x8  qf0 = Qp[lane];
    const bf16x8  qf1 = Qp[64 + lane];
    const bf16x8* Kp = Kf + (size_t)b * 128 * 2 * 64;
    const bf16x8* Vp = Vf + (size_t)b * 128 * 4 * 64;

    // staging map: chunk c (of 384 per tile) -> slot c>>6 [K0,K1,V00,V01,V10,V11], lane c&63
    const int s0i = t >> 6;            // chunk t      -> slots 0..3
    const int l0  = t & 63;
    // thread t<128 also stages chunk 256+t -> slots 4..5
    const bool two = (t < 128);
    const int s1i = 4 + (t >> 6);

    #define SRC_OF(SLOT, NX) ((SLOT) < 2 ? (Kp + ((size_t)(NX) * 2 + (SLOT)) * 64) \
                                         : (Vp + ((size_t)(NX) * 4 + ((SLOT) - 2)) * 64))

    // prologue: stage tile 0 -> buf 0
    {
        uint4 st0 = *(const uint4*)(SRC_OF(s0i, 0) + l0);
        uint4 st1 = two ? *(const uint4*)(SRC_OF(s1i, 0) + l0) : make_uint4(0, 0, 0, 0);
        *(uint4*)(kvbuf + t * 16) = st0;
        if (two) *(uint4*)(kvbuf + 4096 + t * 16) = st1;
    }
    __syncthreads();

    f32x16 o0 = {}, o1 = {};
    float m2 = -1e30f, lacc = 0.f;

    for (int kvt = 0; kvt < 128; ++kvt) {
        // issue next-tile loads early (latency hidden under compute)
        uint4 st0, st1;
        if (kvt < 127) {
            st0 = *(const uint4*)(SRC_OF(s0i, kvt + 1) + l0);
            if (two) st1 = *(const uint4*)(SRC_OF(s1i, kvt + 1) + l0);
        }

        const bf16x8* bc = (const bf16x8*)(kvbuf + (kvt & 1) * 6144);
        const bf16x8 kf0 = bc[lane];
        const bf16x8 kf1 = bc[64 + lane];
        const bf16x8 v00 = bc[128 + lane];
        const bf16x8 v01 = bc[192 + lane];
        const bf16x8 v10 = bc[256 + lane];
        const bf16x8 v11 = bc[320 + lane];

        // S^T tile: rows = kpos(32), cols = q; D=32 -> 2 chained MFMAs
        f32x16 s;
        {
            f32x16 z = {};
            s = __builtin_amdgcn_mfma_f32_32x32x16_bf16(kf0, qf0, z, 0, 0, 0);
            s = __builtin_amdgcn_mfma_f32_32x32x16_bf16(kf1, qf1, s, 0, 0, 0);
        }

        // tree max (folds to v_max3) over own 16
        float a0 = fmaxf(fmaxf(s[0], s[1]), fmaxf(s[2], s[3]));
        float a1 = fmaxf(fmaxf(s[4], s[5]), fmaxf(s[6], s[7]));
        float a2 = fmaxf(fmaxf(s[8], s[9]), fmaxf(s[10], s[11]));
        float a3 = fmaxf(fmaxf(s[12], s[13]), fmaxf(s[14], s[15]));
        const float mx = fmaxf(fmaxf(a0, a1), fmaxf(a2, a3));
        if (__any(mx * LOG2E > m2 + 8.0f)) {   // defer-max: rare, pair shfl only here
            const float fullmx = fmaxf(mx, __shfl_xor(mx, 32, 64));
            const float m2n = fmaxf(m2, fullmx * LOG2E);
            const float sc = exp2f(m2 - m2n);
            lacc *= sc;
            #pragma unroll
            for (int i = 0; i < 16; ++i) { o0[i] *= sc; o1[i] *= sc; }
            m2 = m2n;
        }
        float p[16];
        #pragma unroll
        for (int i = 0; i < 16; ++i) p[i] = exp2f(fmaf(s[i], LOG2E, -m2));
        // tree sum; pair-combine deferred to epilogue (m2 sequence is pair-identical)
        float b0 = (p[0] + p[1]) + (p[2] + p[3]);
        float b1 = (p[4] + p[5]) + (p[6] + p[7]);
        float b2 = (p[8] + p[9]) + (p[10] + p[11]);
        float b3 = (p[12] + p[13]) + (p[14] + p[15]);
        lacc += (b0 + b1) + (b2 + b3);

        // P -> B-frag directly (V k-order permuted at pack time; no lane exchange)
        const bf16x8 pf0 = mkfrag(cvtpk(p[0],  p[1]),  cvtpk(p[2],  p[3]),
                                  cvtpk(p[4],  p[5]),  cvtpk(p[6],  p[7]));
        const bf16x8 pf1 = mkfrag(cvtpk(p[8],  p[9]),  cvtpk(p[10], p[11]),
                                  cvtpk(p[12], p[13]), cvtpk(p[14], p[15]));

        // O^T += V^T x P^T
        o0 = __builtin_amdgcn_mfma_f32_32x32x16_bf16(v00, pf0, o0, 0, 0, 0);
        o0 = __builtin_amdgcn_mfma_f32_32x32x16_bf16(v01, pf1, o0, 0, 0, 0);
        o1 = __builtin_amdgcn_mfma_f32_32x32x16_bf16(v10, pf0, o1, 0, 0, 0);
        o1 = __builtin_amdgcn_mfma_f32_32x32x16_bf16(v11, pf1, o1, 0, 0, 0);

        // write next tile into the other buffer (safe: nobody reads it this iter)
        if (kvt < 127) {
            unsigned char* bo = kvbuf + ((kvt + 1) & 1) * 6144;
            *(uint4*)(bo + t * 16) = st0;
            if (two) *(uint4*)(bo + 4096 + t * 16) = st1;
        }
        __syncthreads();
    }
    #undef SRC_OF

    // ---- epilogue: out[b][c][n] = g * O^T[c][q]/l + x[b][c][n], n = q ----
    const float g = gamma[0];
    const float lt = lacc + __shfl_xor(lacc, 32, 64);
    const float rl = 1.0f / lt;
    const int n = qt * 32 + (lane & 31);
    const int hi1 = lane >> 5;
    #pragma unroll
    for (int r = 0; r < 16; ++r) {
        const int c0r = (r & 3) + 8 * (r >> 2) + 4 * hi1;
        {
            const size_t idx = (((size_t)b * 64 + c0r) << 12) + n;
            out[idx] = g * o0[r] * rl + x[idx];
        }
        {
            const size_t idx = (((size_t)b * 64 + 32 + c0r) << 12) + n;
            out[idx] = g * o1[r] * rl + x[idx];
        }
    }
}

extern "C" void kernel_launch(void* const* d_in, const int* in_sizes, int n_in,
                              void* d_out, int out_size, void* d_ws, size_t ws_size,
                              hipStream_t stream) {
    const float* x     = (const float*)d_in[0];
    const float* w1    = (const float*)d_in[1];
    const float* w2    = (const float*)d_in[2];
    const float* w3    = (const float*)d_in[3];
    const float* gamma = (const float*)d_in[4];
    float* out = (float*)d_out;

    uint4* Qf = (uint4*)d_ws;                        // 4 MB
    uint4* Kf = Qf + (size_t)Bn * 128 * 2 * 64;      // 4 MB
    uint4* Vf = Kf + (size_t)Bn * 128 * 2 * 64;      // 8 MB

    qkv_kernel<<<512, 256, 0, stream>>>(x, w1, w2, w3, Qf, Kf, Vf);
    attn_kernel<<<512, 256, 0, stream>>>((const bf16x8*)Qf, (const bf16x8*)Kf,
                                         (const bf16x8*)Vf, x, gamma, out);
}